// Round 4
// baseline (182.107 us; speedup 1.0000x reference)
//
#include <hip/hip_runtime.h>

#define NEDGE 625000
#define NNODE 50000
#define NTILES ((NEDGE + 127) / 128)   // 4883
#define TPB 4                          // edge tiles per block
#define WPITCH 136  // lW pitch in shorts: 272 B rows -> 2-way bank aliasing on b128 (free)
#define EPITCH 68   // uv epilogue pitch in shorts

typedef __bf16 bf16x8 __attribute__((ext_vector_type(8)));
typedef __bf16 bf16x4 __attribute__((ext_vector_type(4)));
typedef unsigned short u16x8 __attribute__((ext_vector_type(8)));
typedef float f32x4 __attribute__((ext_vector_type(4)));
typedef float f32x8 __attribute__((ext_vector_type(8)));

__device__ __forceinline__ unsigned short f32_bf16(float f) {
  unsigned int u = __float_as_uint(f);
  u += 0x7FFFu + ((u >> 16) & 1u);  // RNE
  return (unsigned short)(u >> 16);
}

// packed bf16 add + relu; RNE bf16 add == f32-add-then-round (same numerics as r3)
__device__ __forceinline__ bf16x8 addrelu8(u16x8 ua, u16x8 ub) {
  bf16x8 a = *(bf16x8*)&ua, b = *(bf16x8*)&ub;
  bf16x8 s = a + b;
  const bf16x8 z = {(__bf16)0.f, (__bf16)0.f, (__bf16)0.f, (__bf16)0.f,
                    (__bf16)0.f, (__bf16)0.f, (__bf16)0.f, (__bf16)0.f};
  return __builtin_elementwise_max(s, z);
}

// ---------------------------------------------------------------------------
// prep: WcatT[j'][k] = W1[k][j'] (j'<128) | W1[128+k][j'-128], bf16
//       W2T[n][k]    = W2[k][n], bf16; idx64_flag from odd-word probe
// ---------------------------------------------------------------------------
__global__ __launch_bounds__(256) void prep_kernel(
    const float* __restrict__ W1, const float* __restrict__ W2,
    const int* __restrict__ ei,
    unsigned short* __restrict__ WcatT, unsigned short* __restrict__ W2T,
    int* __restrict__ idx64_flag)
{
  int i = blockIdx.x * 256 + threadIdx.x;
  if (i < 256 * 128) {
    int jp = i >> 7, k = i & 127;
    float v = (jp < 128) ? W1[k * 128 + jp] : W1[(128 + k) * 128 + (jp - 128)];
    WcatT[jp * 128 + k] = f32_bf16(v);
  } else if (i < 256 * 128 + 64 * 128) {
    int i2 = i - 256 * 128;
    int n = i2 >> 7, k = i2 & 127;
    W2T[n * 128 + k] = f32_bf16(W2[k * 64 + n]);
  }
  if (i == 0) {
    int allz = 1;
    for (int j = 1; j < 64; j += 2) allz &= (ei[j] == 0);
    *idx64_flag = allz;
  }
}

// ---------------------------------------------------------------------------
// uv: UV[n][0:128] = z@W1_top + b1, UV[n][128:256] = z@W1_bot  (bf16)
// nc split across blocks: grid = 391*4, block = 128 rows x 64 cols.
// ---------------------------------------------------------------------------
__global__ __launch_bounds__(256) void uv_kernel(
    const float* __restrict__ z, const float* __restrict__ b1,
    const unsigned short* __restrict__ WcatT,
    unsigned short* __restrict__ UV)
{
  __shared__ unsigned short st[4 * 32 * EPITCH];
  const int t = threadIdx.x, wave = t >> 6, lane = t & 63, c = lane & 15, q = lane >> 4;
  const int mtile = blockIdx.x >> 2, nc = blockIdx.x & 3;
  const int mbase = mtile * 128 + wave * 32;
  const int rA = mbase + c, rB = mbase + 16 + c;
  const int rAc = (rA < NNODE) ? rA : 0;
  const int rBc = (rB < NNODE) ? rB : 0;

  // A-fragments direct from fp32 z; packed cvt to bf16
  bf16x8 a0[4], a1[4];
  {
    const float* zA = z + (size_t)rAc * 128 + q * 8;
    const float* zB = z + (size_t)rBc * 128 + q * 8;
#pragma unroll
    for (int kt = 0; kt < 4; ++kt) {
      f32x8 vA = *(const f32x8*)(zA + kt * 32);
      f32x8 vB = *(const f32x8*)(zB + kt * 32);
      a0[kt] = __builtin_convertvector(vA, bf16x8);
      a1[kt] = __builtin_convertvector(vB, bf16x8);
    }
  }

  f32x4 acc[2][4];
#pragma unroll
  for (int mt = 0; mt < 2; ++mt)
#pragma unroll
    for (int nt = 0; nt < 4; ++nt) {
      f32x4 zz = {0.f, 0.f, 0.f, 0.f};
      acc[mt][nt] = zz;
    }

#pragma unroll
  for (int kt = 0; kt < 4; ++kt) {
#pragma unroll
    for (int nt = 0; nt < 4; ++nt) {
      bf16x8 bb = *(const bf16x8*)(WcatT + (size_t)(nc * 64 + nt * 16 + c) * 128 + kt * 32 + q * 8);
      acc[0][nt] = __builtin_amdgcn_mfma_f32_16x16x32_bf16(a0[kt], bb, acc[0][nt], 0, 0, 0);
      acc[1][nt] = __builtin_amdgcn_mfma_f32_16x16x32_bf16(a1[kt], bb, acc[1][nt], 0, 0, 0);
    }
  }

  float badd[4];
#pragma unroll
  for (int nt = 0; nt < 4; ++nt) {
    int col = nc * 64 + nt * 16 + c;
    badd[nt] = (col < 128) ? b1[col] : 0.f;
  }

  unsigned short* my = &st[wave * 32 * EPITCH];
#pragma unroll
  for (int mt = 0; mt < 2; ++mt)
#pragma unroll
    for (int nt = 0; nt < 4; ++nt) {
      f32x4 v = acc[mt][nt];
      f32x4 vb = {v[0] + badd[nt], v[1] + badd[nt], v[2] + badd[nt], v[3] + badd[nt]};
      bf16x4 bv = __builtin_convertvector(vb, bf16x4);
      const unsigned short* pv = (const unsigned short*)&bv;
#pragma unroll
      for (int reg = 0; reg < 4; ++reg)
        my[(mt * 16 + q * 4 + reg) * EPITCH + nt * 16 + c] = pv[reg];
    }
  __asm__ volatile("s_waitcnt lgkmcnt(0)" ::: "memory");

  {  // lane -> (row, half): 32 shorts (64 B) vectorized store
    int lrow = lane >> 1, half = lane & 1;
    int grow = mbase + lrow;
    u16x8 d0 = *(u16x8*)&my[lrow * EPITCH + half * 32 + 0];
    u16x8 d1 = *(u16x8*)&my[lrow * EPITCH + half * 32 + 8];
    u16x8 d2 = *(u16x8*)&my[lrow * EPITCH + half * 32 + 16];
    u16x8 d3 = *(u16x8*)&my[lrow * EPITCH + half * 32 + 24];
    if (grow < NNODE) {
      u16x8* dst = (u16x8*)(UV + (size_t)grow * 256 + nc * 64 + half * 32);
      dst[0] = d0; dst[1] = d1; dst[2] = d2; dst[3] = d3;
    }
  }
}

// ---------------------------------------------------------------------------
// edge: TPB tiles per block; W2T staged once; idx up-front; next tile's
// gathers issued before current MFMA loop (software pipeline, same reg set).
// ---------------------------------------------------------------------------
__global__ __launch_bounds__(256) void edge_kernel(
    const int* __restrict__ ei,
    const unsigned short* __restrict__ UV,
    const unsigned short* __restrict__ W2T,
    const float* __restrict__ b2, const float* __restrict__ W3,
    const float* __restrict__ b3, const int* __restrict__ idx64_flag,
    float* __restrict__ out)
{
  __shared__ unsigned short lW[64 * WPITCH];
  const int t = threadIdx.x, wave = t >> 6, lane = t & 63, c = lane & 15, q = lane >> 4;

  {  // stage W2T once per block
    int n = t >> 2, qd = t & 3;
    const u16x8* src = (const u16x8*)(W2T + n * 128 + qd * 32);
    u16x8* dst = (u16x8*)(&lW[n * WPITCH + qd * 32]);
#pragma unroll
    for (int i = 0; i < 4; ++i) dst[i] = src[i];
  }
  __syncthreads();  // only barrier

  const int tile0 = blockIdx.x * TPB;
  int sA[TPB], dA[TPB], sB[TPB], dB[TPB];
  {
    const int is64 = *idx64_flag;
#pragma unroll
    for (int tt = 0; tt < TPB; ++tt) {
      int ebase = (tile0 + tt) * 128 + wave * 32;
      int eA = ebase + c, eB = ebase + 16 + c;
      int eAc = (eA < NEDGE) ? eA : 0;
      int eBc = (eB < NEDGE) ? eB : 0;
      if (is64) {
        const long long* e64 = (const long long*)ei;
        sA[tt] = (int)e64[eAc]; dA[tt] = (int)e64[NEDGE + eAc];
        sB[tt] = (int)e64[eBc]; dB[tt] = (int)e64[NEDGE + eBc];
      } else {
        sA[tt] = ei[eAc]; dA[tt] = ei[NEDGE + eAc];
        sB[tt] = ei[eBc]; dB[tt] = ei[NEDGE + eBc];
      }
    }
  }

  float b2v[4], w3v[4];
#pragma unroll
  for (int nt = 0; nt < 4; ++nt) {
    int n = nt * 16 + c;
    b2v[nt] = b2[n];
    w3v[nt] = W3[n];
  }
  const float bias3 = b3[0];

  u16x8 rAu[4], rAv[4], rBu[4], rBv[4];
#define GATHER(tt)                                                           \
  {                                                                          \
    const u16x8* pAu = (const u16x8*)(UV + (size_t)sA[tt] * 256) + q;        \
    const u16x8* pAv = (const u16x8*)(UV + (size_t)dA[tt] * 256 + 128) + q;  \
    const u16x8* pBu = (const u16x8*)(UV + (size_t)sB[tt] * 256) + q;        \
    const u16x8* pBv = (const u16x8*)(UV + (size_t)dB[tt] * 256 + 128) + q;  \
    _Pragma("unroll") for (int kt = 0; kt < 4; ++kt) {                       \
      rAu[kt] = pAu[kt * 4];                                                 \
      rAv[kt] = pAv[kt * 4];                                                 \
      rBu[kt] = pBu[kt * 4];                                                 \
      rBv[kt] = pBv[kt * 4];                                                 \
    }                                                                        \
  }

  GATHER(0)

  for (int tt = 0; tt < TPB; ++tt) {
    // consume current gathers -> A-frags (packed bf16 add+relu)
    bf16x8 a0[4], a1[4];
#pragma unroll
    for (int kt = 0; kt < 4; ++kt) {
      a0[kt] = addrelu8(rAu[kt], rAv[kt]);
      a1[kt] = addrelu8(rBu[kt], rBv[kt]);
    }
    if (tt + 1 < TPB) GATHER(tt + 1)  // issue next gathers; latency hidden by MFMA+epilogue

    f32x4 acc[2][4];
#pragma unroll
    for (int mt = 0; mt < 2; ++mt)
#pragma unroll
      for (int nt = 0; nt < 4; ++nt) {
        f32x4 zz = {0.f, 0.f, 0.f, 0.f};
        acc[mt][nt] = zz;
      }

#pragma unroll
    for (int kt = 0; kt < 4; ++kt) {
#pragma unroll
      for (int nt = 0; nt < 4; ++nt) {
        bf16x8 bb = *(const bf16x8*)(&lW[(nt * 16 + c) * WPITCH + kt * 32 + q * 8]);
        acc[0][nt] = __builtin_amdgcn_mfma_f32_16x16x32_bf16(a0[kt], bb, acc[0][nt], 0, 0, 0);
        acc[1][nt] = __builtin_amdgcn_mfma_f32_16x16x32_bf16(a1[kt], bb, acc[1][nt], 0, 0, 0);
      }
    }

    const int ebase = (tile0 + tt) * 128 + wave * 32;
#pragma unroll
    for (int mt = 0; mt < 2; ++mt) {
      float p0 = 0.f, p1 = 0.f, p2 = 0.f, p3 = 0.f;
#pragma unroll
      for (int nt = 0; nt < 4; ++nt) {
        p0 += fmaxf(acc[mt][nt][0] + b2v[nt], 0.f) * w3v[nt];
        p1 += fmaxf(acc[mt][nt][1] + b2v[nt], 0.f) * w3v[nt];
        p2 += fmaxf(acc[mt][nt][2] + b2v[nt], 0.f) * w3v[nt];
        p3 += fmaxf(acc[mt][nt][3] + b2v[nt], 0.f) * w3v[nt];
      }
#pragma unroll
      for (int m = 1; m < 16; m <<= 1) {
        p0 += __shfl_xor(p0, m, 64);
        p1 += __shfl_xor(p1, m, 64);
        p2 += __shfl_xor(p2, m, 64);
        p3 += __shfl_xor(p3, m, 64);
      }
      if (c == 0) {
        int eb = ebase + mt * 16 + q * 4;
        if (eb + 0 < NEDGE) out[eb + 0] = p0 + bias3;
        if (eb + 1 < NEDGE) out[eb + 1] = p1 + bias3;
        if (eb + 2 < NEDGE) out[eb + 2] = p2 + bias3;
        if (eb + 3 < NEDGE) out[eb + 3] = p3 + bias3;
      }
    }
  }
#undef GATHER
}

extern "C" void kernel_launch(void* const* d_in, const int* in_sizes, int n_in,
                              void* d_out, int out_size, void* d_ws, size_t ws_size,
                              hipStream_t stream) {
  const float* z  = (const float*)d_in[0];
  const int*   ei = (const int*)d_in[1];
  const float* W1 = (const float*)d_in[2];
  const float* b1 = (const float*)d_in[3];
  const float* W2 = (const float*)d_in[4];
  const float* b2 = (const float*)d_in[5];
  const float* W3 = (const float*)d_in[6];
  const float* b3 = (const float*)d_in[7];
  float* out = (float*)d_out;

  unsigned short* UV    = (unsigned short*)d_ws;       // 50000*256 bf16 = 25.6 MB
  unsigned short* WcatT = UV + (size_t)NNODE * 256;    // 256*128 bf16
  unsigned short* W2T   = WcatT + 256 * 128;           // 64*128 bf16
  int* idx64_flag       = (int*)(W2T + 64 * 128);

  prep_kernel<<<dim3(160), dim3(256), 0, stream>>>(W1, W2, ei, WcatT, W2T, idx64_flag);
  uv_kernel<<<dim3(((NNODE + 127) / 128) * 4), dim3(256), 0, stream>>>(z, b1, WcatT, UV);
  edge_kernel<<<dim3((NTILES + TPB - 1) / TPB), dim3(256), 0, stream>>>(
      ei, UV, W2T, b2, W3, b3, idx64_flag, out);
}

// Round 5
// 160.166 us; speedup vs baseline: 1.1370x; 1.1370x over previous
//
#include <hip/hip_runtime.h>

#define NEDGE 625000
#define NNODE 50000
#define NTILES ((NEDGE + 127) / 128)   // 4883
#define WPITCH 136  // lW pitch in shorts: 272 B rows -> 2-way bank aliasing on b128 (free)
#define EPITCH 68   // uv epilogue pitch in shorts

typedef __bf16 bf16x8 __attribute__((ext_vector_type(8)));
typedef __bf16 bf16x4 __attribute__((ext_vector_type(4)));
typedef unsigned short u16x8 __attribute__((ext_vector_type(8)));
typedef float f32x4 __attribute__((ext_vector_type(4)));
typedef float f32x8 __attribute__((ext_vector_type(8)));

__device__ __forceinline__ unsigned short f32_bf16(float f) {
  unsigned int u = __float_as_uint(f);
  u += 0x7FFFu + ((u >> 16) & 1u);  // RNE
  return (unsigned short)(u >> 16);
}

// packed bf16 add + relu; RNE bf16 add == f32-add-then-round (absmax-verified r4)
__device__ __forceinline__ bf16x8 addrelu8(u16x8 ua, u16x8 ub) {
  bf16x8 a = *(bf16x8*)&ua, b = *(bf16x8*)&ub;
  bf16x8 s = a + b;
  const bf16x8 z = {(__bf16)0.f, (__bf16)0.f, (__bf16)0.f, (__bf16)0.f,
                    (__bf16)0.f, (__bf16)0.f, (__bf16)0.f, (__bf16)0.f};
  return __builtin_elementwise_max(s, z);
}

// ---------------------------------------------------------------------------
// prep: WcatT[j'][k] = W1[k][j'] (j'<128) | W1[128+k][j'-128], bf16
//       W2T[n][k]    = W2[k][n], bf16; idx64_flag from odd-word probe
// ---------------------------------------------------------------------------
__global__ __launch_bounds__(256) void prep_kernel(
    const float* __restrict__ W1, const float* __restrict__ W2,
    const int* __restrict__ ei,
    unsigned short* __restrict__ WcatT, unsigned short* __restrict__ W2T,
    int* __restrict__ idx64_flag)
{
  int i = blockIdx.x * 256 + threadIdx.x;
  if (i < 256 * 128) {
    int jp = i >> 7, k = i & 127;
    float v = (jp < 128) ? W1[k * 128 + jp] : W1[(128 + k) * 128 + (jp - 128)];
    WcatT[jp * 128 + k] = f32_bf16(v);
  } else if (i < 256 * 128 + 64 * 128) {
    int i2 = i - 256 * 128;
    int n = i2 >> 7, k = i2 & 127;
    W2T[n * 128 + k] = f32_bf16(W2[k * 64 + n]);
  }
  if (i == 0) {
    int allz = 1;
    for (int j = 1; j < 64; j += 2) allz &= (ei[j] == 0);
    *idx64_flag = allz;
  }
}

// ---------------------------------------------------------------------------
// uv: UV[n][0:128] = z@W1_top + b1, UV[n][128:256] = z@W1_bot  (bf16)
// 32 rows/block, wave w handles nc=w (z tile read once, reused 4x via L1).
// Grid 1563 -> 6.1 blocks/CU. Barrier-free.
// ---------------------------------------------------------------------------
__global__ __launch_bounds__(256) void uv_kernel(
    const float* __restrict__ z, const float* __restrict__ b1,
    const unsigned short* __restrict__ WcatT,
    unsigned short* __restrict__ UV)
{
  __shared__ unsigned short st[4 * 32 * EPITCH];
  const int t = threadIdx.x, wave = t >> 6, lane = t & 63, c = lane & 15, q = lane >> 4;
  const int nc = wave;
  const int mbase = blockIdx.x * 32;
  const int rA = mbase + c, rB = mbase + 16 + c;
  const int rAc = (rA < NNODE) ? rA : 0;
  const int rBc = (rB < NNODE) ? rB : 0;

  // A-fragments direct from fp32 z; packed cvt to bf16
  bf16x8 a0[4], a1[4];
  {
    const float* zA = z + (size_t)rAc * 128 + q * 8;
    const float* zB = z + (size_t)rBc * 128 + q * 8;
#pragma unroll
    for (int kt = 0; kt < 4; ++kt) {
      f32x8 vA = *(const f32x8*)(zA + kt * 32);
      f32x8 vB = *(const f32x8*)(zB + kt * 32);
      a0[kt] = __builtin_convertvector(vA, bf16x8);
      a1[kt] = __builtin_convertvector(vB, bf16x8);
    }
  }

  f32x4 acc[2][4];
#pragma unroll
  for (int mt = 0; mt < 2; ++mt)
#pragma unroll
    for (int nt = 0; nt < 4; ++nt) {
      f32x4 zz = {0.f, 0.f, 0.f, 0.f};
      acc[mt][nt] = zz;
    }

#pragma unroll
  for (int kt = 0; kt < 4; ++kt) {
#pragma unroll
    for (int nt = 0; nt < 4; ++nt) {
      bf16x8 bb = *(const bf16x8*)(WcatT + (size_t)(nc * 64 + nt * 16 + c) * 128 + kt * 32 + q * 8);
      acc[0][nt] = __builtin_amdgcn_mfma_f32_16x16x32_bf16(a0[kt], bb, acc[0][nt], 0, 0, 0);
      acc[1][nt] = __builtin_amdgcn_mfma_f32_16x16x32_bf16(a1[kt], bb, acc[1][nt], 0, 0, 0);
    }
  }

  float badd[4];
#pragma unroll
  for (int nt = 0; nt < 4; ++nt) {
    int col = nc * 64 + nt * 16 + c;
    badd[nt] = (col < 128) ? b1[col] : 0.f;
  }

  unsigned short* my = &st[wave * 32 * EPITCH];
#pragma unroll
  for (int mt = 0; mt < 2; ++mt)
#pragma unroll
    for (int nt = 0; nt < 4; ++nt) {
      f32x4 v = acc[mt][nt];
      f32x4 vb = {v[0] + badd[nt], v[1] + badd[nt], v[2] + badd[nt], v[3] + badd[nt]};
      bf16x4 bv = __builtin_convertvector(vb, bf16x4);
      const unsigned short* pv = (const unsigned short*)&bv;
#pragma unroll
      for (int reg = 0; reg < 4; ++reg)
        my[(mt * 16 + q * 4 + reg) * EPITCH + nt * 16 + c] = pv[reg];
    }
  __asm__ volatile("s_waitcnt lgkmcnt(0)" ::: "memory");

  {  // lane -> (row, half): 32 shorts (64 B) vectorized store
    int lrow = lane >> 1, half = lane & 1;
    int grow = mbase + lrow;
    u16x8 d0 = *(u16x8*)&my[lrow * EPITCH + half * 32 + 0];
    u16x8 d1 = *(u16x8*)&my[lrow * EPITCH + half * 32 + 8];
    u16x8 d2 = *(u16x8*)&my[lrow * EPITCH + half * 32 + 16];
    u16x8 d3 = *(u16x8*)&my[lrow * EPITCH + half * 32 + 24];
    if (grow < NNODE) {
      u16x8* dst = (u16x8*)(UV + (size_t)grow * 256 + nc * 64 + half * 32);
      dst[0] = d0; dst[1] = d1; dst[2] = d2; dst[3] = d3;
    }
  }
}

// ---------------------------------------------------------------------------
// edge (r3 structure + packed addrelu): gather A-frags directly from UV,
// one 128-edge tile per block, W2T in LDS, fp32 epilogue.
// ---------------------------------------------------------------------------
__global__ __launch_bounds__(256) void edge_kernel(
    const int* __restrict__ ei,
    const unsigned short* __restrict__ UV,
    const unsigned short* __restrict__ W2T,
    const float* __restrict__ b2, const float* __restrict__ W3,
    const float* __restrict__ b3, const int* __restrict__ idx64_flag,
    float* __restrict__ out)
{
  __shared__ unsigned short lW[64 * WPITCH];
  const int t = threadIdx.x, wave = t >> 6, lane = t & 63, c = lane & 15, q = lane >> 4;

  {  // stage W2T once (16 KB shared by all waves)
    int n = t >> 2, qd = t & 3;
    const u16x8* src = (const u16x8*)(W2T + n * 128 + qd * 32);
    u16x8* dst = (u16x8*)(&lW[n * WPITCH + qd * 32]);
#pragma unroll
    for (int i = 0; i < 4; ++i) dst[i] = src[i];
  }
  __syncthreads();  // the only barrier

  const int ebase = blockIdx.x * 128 + wave * 32;
  const int eA = ebase + c, eB = ebase + 16 + c;
  const int eAc = (eA < NEDGE) ? eA : 0;
  const int eBc = (eB < NEDGE) ? eB : 0;
  int sA, dA, sB, dB;
  if (*idx64_flag) {
    const long long* e64 = (const long long*)ei;
    sA = (int)e64[eAc]; dA = (int)e64[NEDGE + eAc];
    sB = (int)e64[eBc]; dB = (int)e64[NEDGE + eBc];
  } else {
    sA = ei[eAc]; dA = ei[NEDGE + eAc];
    sB = ei[eBc]; dB = ei[NEDGE + eBc];
  }

  // 16 independent 16B gather loads (4 per kt)
  const u16x8* pAu = (const u16x8*)(UV + (size_t)sA * 256) + q;
  const u16x8* pAv = (const u16x8*)(UV + (size_t)dA * 256 + 128) + q;
  const u16x8* pBu = (const u16x8*)(UV + (size_t)sB * 256) + q;
  const u16x8* pBv = (const u16x8*)(UV + (size_t)dB * 256 + 128) + q;
  u16x8 rAu[4], rAv[4], rBu[4], rBv[4];
#pragma unroll
  for (int kt = 0; kt < 4; ++kt) {
    rAu[kt] = pAu[kt * 4];
    rAv[kt] = pAv[kt * 4];
    rBu[kt] = pBu[kt * 4];
    rBv[kt] = pBv[kt * 4];
  }

  f32x4 acc[2][4];
#pragma unroll
  for (int mt = 0; mt < 2; ++mt)
#pragma unroll
    for (int nt = 0; nt < 4; ++nt) {
      f32x4 zz = {0.f, 0.f, 0.f, 0.f};
      acc[mt][nt] = zz;
    }

#pragma unroll
  for (int kt = 0; kt < 4; ++kt) {
    bf16x8 a0 = addrelu8(rAu[kt], rAv[kt]);
    bf16x8 a1 = addrelu8(rBu[kt], rBv[kt]);
#pragma unroll
    for (int nt = 0; nt < 4; ++nt) {
      bf16x8 bb = *(const bf16x8*)(&lW[(nt * 16 + c) * WPITCH + kt * 32 + q * 8]);
      acc[0][nt] = __builtin_amdgcn_mfma_f32_16x16x32_bf16(a0, bb, acc[0][nt], 0, 0, 0);
      acc[1][nt] = __builtin_amdgcn_mfma_f32_16x16x32_bf16(a1, bb, acc[1][nt], 0, 0, 0);
    }
  }

  // layer-2 bias+relu and layer-3 dot in fp32; reduce over the 16 c-lanes
  float b2v[4], w3v[4];
#pragma unroll
  for (int nt = 0; nt < 4; ++nt) {
    int n = nt * 16 + c;
    b2v[nt] = b2[n];
    w3v[nt] = W3[n];
  }
  const float bias3 = b3[0];

#pragma unroll
  for (int mt = 0; mt < 2; ++mt) {
    float p0 = 0.f, p1 = 0.f, p2 = 0.f, p3 = 0.f;
#pragma unroll
    for (int nt = 0; nt < 4; ++nt) {
      p0 += fmaxf(acc[mt][nt][0] + b2v[nt], 0.f) * w3v[nt];
      p1 += fmaxf(acc[mt][nt][1] + b2v[nt], 0.f) * w3v[nt];
      p2 += fmaxf(acc[mt][nt][2] + b2v[nt], 0.f) * w3v[nt];
      p3 += fmaxf(acc[mt][nt][3] + b2v[nt], 0.f) * w3v[nt];
    }
#pragma unroll
    for (int m = 1; m < 16; m <<= 1) {
      p0 += __shfl_xor(p0, m, 64);
      p1 += __shfl_xor(p1, m, 64);
      p2 += __shfl_xor(p2, m, 64);
      p3 += __shfl_xor(p3, m, 64);
    }
    if (c == 0) {
      int eb = ebase + mt * 16 + q * 4;
      if (eb + 0 < NEDGE) out[eb + 0] = p0 + bias3;
      if (eb + 1 < NEDGE) out[eb + 1] = p1 + bias3;
      if (eb + 2 < NEDGE) out[eb + 2] = p2 + bias3;
      if (eb + 3 < NEDGE) out[eb + 3] = p3 + bias3;
    }
  }
}

extern "C" void kernel_launch(void* const* d_in, const int* in_sizes, int n_in,
                              void* d_out, int out_size, void* d_ws, size_t ws_size,
                              hipStream_t stream) {
  const float* z  = (const float*)d_in[0];
  const int*   ei = (const int*)d_in[1];
  const float* W1 = (const float*)d_in[2];
  const float* b1 = (const float*)d_in[3];
  const float* W2 = (const float*)d_in[4];
  const float* b2 = (const float*)d_in[5];
  const float* W3 = (const float*)d_in[6];
  const float* b3 = (const float*)d_in[7];
  float* out = (float*)d_out;

  unsigned short* UV    = (unsigned short*)d_ws;       // 50000*256 bf16 = 25.6 MB
  unsigned short* WcatT = UV + (size_t)NNODE * 256;    // 256*128 bf16
  unsigned short* W2T   = WcatT + 256 * 128;           // 64*128 bf16
  int* idx64_flag       = (int*)(W2T + 64 * 128);

  prep_kernel<<<dim3(160), dim3(256), 0, stream>>>(W1, W2, ei, WcatT, W2T, idx64_flag);
  uv_kernel<<<dim3((NNODE + 31) / 32), dim3(256), 0, stream>>>(z, b1, WcatT, UV);
  edge_kernel<<<dim3(NTILES), dim3(256), 0, stream>>>(
      ei, UV, W2T, b2, W3, b3, idx64_flag, out);
}